// Round 1
// baseline (921.684 us; speedup 1.0000x reference)
//
#include <hip/hip_runtime.h>
#include <math.h>

#define NB 16
#define NT 24
#define HP 56
#define WP 56
#define NF 32
#define ND (HP*WP*NF)   // 100352
#define NHPQ 14
#define LN_EPS 1e-3f

typedef __attribute__((ext_vector_type(8))) short short8;
typedef __attribute__((ext_vector_type(4))) float floatx4;

__device__ __forceinline__ float tanh_fast(float x){
    float e = __expf(2.0f*x);
    return 1.0f - 2.0f*__builtin_amdgcn_rcpf(e + 1.0f);
}
__device__ __forceinline__ float hsig(float z){
    return fminf(fmaxf(z*0.2f + 0.5f, 0.0f), 1.0f);
}
__device__ __forceinline__ ushort f2bf(float v){  // fp32 -> bf16 bits, RNE
    unsigned u = __float_as_uint(v);
    return (ushort)((u + 0x7fffu + ((u >> 16) & 1u)) >> 16);
}

// Persistent fused ConvLSTM+LN. One block per (hpq, b) tile, resident for all
// 24 timesteps. 224 blocks <= 256 CUs; 113 KB LDS physically forces 1 block/CU
// so all blocks are co-resident -> spin-waits cannot deadlock.
//  - c lives in registers (no cbuf traffic)
//  - h lives in LDS; only 2 halo rows/block cross blocks per step (bf16,
//    parity double-buffered, release/acquire flag per (t,b,hpq))
//  - U/Wk weights converted to bf16 in LDS once, read conflict-free
//  - LN fused: h[t] held in regs one iteration; once stats(b,t) counter==14,
//    out[t] is written already normalized (ln_scale pass eliminated)
__global__ __launch_bounds__(256, 1)
void convlstm_persist(const float* __restrict__ x,      // (B,T,112,112,3)
                      const float* __restrict__ Wk,     // (3,3,3,128)
                      const float* __restrict__ Uk,     // (3,3,32,128)
                      const float* __restrict__ bias,   // (128)
                      const float* __restrict__ gamma,  // (D)
                      const float* __restrict__ beta,   // (D)
                      ushort* __restrict__ hbuf0,       // (B,56,56,32) bf16 halo
                      ushort* __restrict__ hbuf1,
                      float* __restrict__ out,          // (B,T,D)
                      float* __restrict__ stats,        // (B*T,2)
                      int* __restrict__ cnt,            // (B*T)
                      int* __restrict__ flags)          // (T,B,14)
{
    __shared__ __attribute__((aligned(16))) ushort h_lds[6*66*32];   // 25344 B
    __shared__ __attribute__((aligned(16))) ushort x_lds[9*344];     //  6192 B
    __shared__ __attribute__((aligned(16))) ushort u_lds[9*128*32];  // 73728 B
    __shared__ __attribute__((aligned(16))) ushort wk_lds[128*32];   //  8192 B
    __shared__ float bcast[2];

    const int tid  = threadIdx.x;
    const int hpq  = blockIdx.x;
    const int b    = blockIdx.y;
    const int lane = tid & 63;
    const int w    = tid >> 6;        // wave id = local hp row
    const int col  = lane & 15;
    const int q    = lane >> 4;
    const int q8   = q * 8;
    const int hp_g = hpq*4 + w;

    // ---- one-time init: zero LDS pads, convert weights to bf16 LDS ----
    for (int e = tid; e < 6*66*32; e += 256) h_lds[e] = 0;
    for (int e = tid; e < 9*344;   e += 256) x_lds[e] = 0;
    for (int e = tid; e < 9*32*128; e += 256){
        int tap = e >> 12, k = (e >> 7) & 31, n = e & 127;
        u_lds[(tap*128 + n)*32 + k] = f2bf(Uk[e]);
    }
    for (int e = tid; e < 128*32; e += 256){
        int n = e >> 5, k = e & 31;
        wk_lds[e] = (k < 27) ? f2bf(Wk[k*128 + n]) : (ushort)0;
    }

    // ---- persistent registers ----
    float bg[8];
    #pragma unroll
    for (int nt = 0; nt < 8; nt++) bg[nt] = bias[nt*16 + col];

    float gr[4][2][4], br[4][2][4], creg[4][2][4], hreg[4][2][4];
    #pragma unroll
    for (int mt = 0; mt < 4; mt++)
      #pragma unroll
      for (int fh = 0; fh < 2; fh++)
        #pragma unroll
        for (int reg = 0; reg < 4; reg++){
            int wp = mt*16 + q*4 + reg;
            creg[mt][fh][reg] = 0.f;
            hreg[mt][fh][reg] = 0.f;
            if (wp < WP){
                size_t idx = (size_t)(hp_g*WP + wp)*NF + fh*16 + col;
                gr[mt][fh][reg] = gamma[idx];
                br[mt][fh][reg] = beta[idx];
            } else { gr[mt][fh][reg] = 0.f; br[mt][fh][reg] = 0.f; }
        }

    __syncthreads();   // init complete

    for (int t = 0; t < NT; ++t){
        // ---- stage x rows 8hpq..8hpq+8 (vectorized fp32->bf16) ----
        {
            const float* xt = x + ((size_t)(b*NT + t))*(112*112*3);
            for (int e = tid; e < 9*84; e += 256){
                int row = e / 84;
                int c4  = e - row*84;
                int rg  = 8*hpq + row;
                if (rg < 112){
                    float4 v = *(const float4*)&xt[rg*336 + c4*4];
                    ushort4 s4 = {f2bf(v.x), f2bf(v.y), f2bf(v.z), f2bf(v.w)};
                    *(ushort4*)&x_lds[row*344 + c4*4] = s4;
                }
            }
        }

        if (t > 0){
            // ---- wait: neighbor halos(t-1) written, stats(t-1) complete ----
            if (tid == 0){
                const int fb = ((t-1)*NB + b)*NHPQ;
                if (hpq > 0)
                    while (__hip_atomic_load(&flags[fb + hpq-1], __ATOMIC_ACQUIRE, __HIP_MEMORY_SCOPE_AGENT) == 0)
                        __builtin_amdgcn_s_sleep(2);
                if (hpq < NHPQ-1)
                    while (__hip_atomic_load(&flags[fb + hpq+1], __ATOMIC_ACQUIRE, __HIP_MEMORY_SCOPE_AGENT) == 0)
                        __builtin_amdgcn_s_sleep(2);
                while (__hip_atomic_load(&cnt[b*NT + t-1], __ATOMIC_ACQUIRE, __HIP_MEMORY_SCOPE_AGENT) < NHPQ)
                    __builtin_amdgcn_s_sleep(2);
                float s  = __hip_atomic_load(&stats[(size_t)(b*NT + t-1)*2],     __ATOMIC_RELAXED, __HIP_MEMORY_SCOPE_AGENT);
                float ss = __hip_atomic_load(&stats[(size_t)(b*NT + t-1)*2 + 1], __ATOMIC_RELAXED, __HIP_MEMORY_SCOPE_AGENT);
                float m  = s * (1.0f/(float)ND);
                float v  = ss * (1.0f/(float)ND) - m*m;
                bcast[0] = m;
                bcast[1] = rsqrtf(v + LN_EPS);
            }
            __syncthreads();                       // B1
            const float mu = bcast[0], rs = bcast[1];

            // ---- stage h halo rows (top->lds row 0, bottom->lds row 5) ----
            {
                const ushort* hsrc = ((t & 1) ? hbuf0 : hbuf1) + (size_t)b*ND;
                for (int e = tid; e < 448; e += 256){
                    int rsel = (e >= 224);
                    int rem  = e - rsel*224;
                    int cg   = rem >> 2, cq = rem & 3;
                    int rg   = rsel ? (hpq*4 + 4) : (hpq*4 - 1);
                    int ldr  = rsel ? 5 : 0;
                    if (rg >= 0 && rg < HP)
                        *(uint4*)&h_lds[(ldr*66 + 1 + cg)*32 + cq*8] =
                            *(const uint4*)&hsrc[((size_t)rg*WP + cg)*NF + cq*8];
                }
            }

            // ---- deferred normalized write of out[t-1] from held regs ----
            {
                float* orow = out + ((size_t)(b*NT + t - 1))*ND;
                #pragma unroll
                for (int mt = 0; mt < 4; mt++)
                  #pragma unroll
                  for (int fh = 0; fh < 2; fh++)
                    #pragma unroll
                    for (int reg = 0; reg < 4; reg++){
                        int wp = mt*16 + q*4 + reg;
                        if (wp < WP)
                            orow[(size_t)(hp_g*WP + wp)*NF + fh*16 + col] =
                                (hreg[mt][fh][reg] - mu)*rs*gr[mt][fh][reg] + br[mt][fh][reg];
                    }
            }
        }
        __syncthreads();                           // B2: x/h staging visible

        // ---- accumulators with bias folded ----
        floatx4 acc[4][8];
        #pragma unroll
        for (int nt = 0; nt < 8; nt++){
            floatx4 bv = (floatx4){bg[nt], bg[nt], bg[nt], bg[nt]};
            #pragma unroll
            for (int mt = 0; mt < 4; mt++) acc[mt][nt] = bv;
        }

        // ---- input conv: one K=32 MFMA step (k>=27 zero) ----
        {
            short8 ax[4];
            #pragma unroll
            for (int mt = 0; mt < 4; mt++){
                int wp = mt*16 + col;
                short8 v;
                #pragma unroll
                for (int j = 0; j < 8; j++){
                    int k = q8 + j;
                    ushort bits = 0;
                    if (k < 27){
                        int dy = k/9; int rr = k - dy*9; int dx = rr/3; int cc = rr - dx*3;
                        int xc = 2*wp + dx; if (xc > 112) xc = 112;
                        bits = x_lds[(2*w + dy)*344 + xc*3 + cc];
                    }
                    v[j] = (short)bits;
                }
                ax[mt] = v;
            }
            #pragma unroll
            for (int nt = 0; nt < 8; nt++){
                short8 bx = *(const short8*)&wk_lds[(nt*16 + col)*32 + q8];
                #pragma unroll
                for (int mt = 0; mt < 4; mt++)
                    acc[mt][nt] = __builtin_amdgcn_mfma_f32_16x16x32_bf16(ax[mt], bx, acc[mt][nt], 0, 0, 0);
            }
        }

        // ---- 9 recurrent taps, K=32 each ----
        if (t > 0){
            #pragma unroll
            for (int tap = 0; tap < 9; tap++){
                int dy = tap/3, dx = tap - dy*3;
                short8 a_[4], bb_[8];
                #pragma unroll
                for (int nt = 0; nt < 8; nt++)
                    bb_[nt] = *(const short8*)&u_lds[(tap*128 + nt*16 + col)*32 + q8];
                #pragma unroll
                for (int mt = 0; mt < 4; mt++)
                    a_[mt] = *(const short8*)&h_lds[((w + dy)*66 + mt*16 + col + dx)*32 + q8];
                #pragma unroll
                for (int mt = 0; mt < 4; mt++)
                    #pragma unroll
                    for (int nt = 0; nt < 8; nt++)
                        acc[mt][nt] = __builtin_amdgcn_mfma_f32_16x16x32_bf16(a_[mt], bb_[nt], acc[mt][nt], 0, 0, 0);
            }
        }
        __syncthreads();                           // B3: all waves done reading h_lds

        // ---- LSTM pointwise epilogue: c,h in regs, h->LDS interior ----
        float lsum = 0.f, lss = 0.f;
        #pragma unroll
        for (int mt = 0; mt < 4; mt++)
          #pragma unroll
          for (int fh = 0; fh < 2; fh++)
            #pragma unroll
            for (int reg = 0; reg < 4; reg++){
                int wp = mt*16 + q*4 + reg;
                float zi = acc[mt][0 + fh][reg];
                float zf = acc[mt][2 + fh][reg];
                float zc = acc[mt][4 + fh][reg];
                float zo = acc[mt][6 + fh][reg];
                float ig = hsig(zi), fg = hsig(zf), og = hsig(zo);
                float cn = fg*creg[mt][fh][reg] + ig*tanh_fast(zc);
                float hv = og*tanh_fast(cn);
                if (wp < WP){
                    creg[mt][fh][reg] = cn;
                    hreg[mt][fh][reg] = hv;
                    h_lds[((w + 1)*66 + 1 + wp)*32 + fh*16 + col] = f2bf(hv);
                    lsum += hv;
                    lss  += hv*hv;
                }
            }

        // ---- halo rows to global (own-wave data; waves 0 and 3 only) ----
        {
            ushort* hdst = ((t & 1) ? hbuf1 : hbuf0) + (size_t)b*ND;
            if (w == 0 || w == 3){
                int rg  = hpq*4 + ((w == 0) ? 0 : 3);
                int ldr = (w == 0) ? 1 : 4;
                for (int e = lane; e < 224; e += 64){
                    int cg = e >> 2, cq = e & 3;
                    *(uint4*)&hdst[((size_t)rg*WP + cg)*NF + cq*8] =
                        *(const uint4*)&h_lds[(ldr*66 + 1 + cg)*32 + cq*8];
                }
            }
        }

        // ---- stats: wave reduce + one atomic pair per wave ----
        #pragma unroll
        for (int off = 32; off > 0; off >>= 1){
            lsum += __shfl_down(lsum, off);
            lss  += __shfl_down(lss, off);
        }
        if (lane == 0){
            atomicAdd(&stats[(size_t)(b*NT + t)*2],     lsum);
            atomicAdd(&stats[(size_t)(b*NT + t)*2 + 1], lss);
        }

        __syncthreads();   // B4: drains all waves' global stores + LDS writes
        if (tid == 0){
            __hip_atomic_fetch_add(&cnt[b*NT + t], 1, __ATOMIC_RELEASE, __HIP_MEMORY_SCOPE_AGENT);
            __hip_atomic_fetch_add(&flags[((size_t)t*NB + b)*NHPQ + hpq], 1, __ATOMIC_RELEASE, __HIP_MEMORY_SCOPE_AGENT);
        }
    }

    // ---- final: normalized write of out[NT-1] ----
    if (tid == 0){
        while (__hip_atomic_load(&cnt[b*NT + NT-1], __ATOMIC_ACQUIRE, __HIP_MEMORY_SCOPE_AGENT) < NHPQ)
            __builtin_amdgcn_s_sleep(2);
        float s  = __hip_atomic_load(&stats[(size_t)(b*NT + NT-1)*2],     __ATOMIC_RELAXED, __HIP_MEMORY_SCOPE_AGENT);
        float ss = __hip_atomic_load(&stats[(size_t)(b*NT + NT-1)*2 + 1], __ATOMIC_RELAXED, __HIP_MEMORY_SCOPE_AGENT);
        float m  = s * (1.0f/(float)ND);
        float v  = ss * (1.0f/(float)ND) - m*m;
        bcast[0] = m;
        bcast[1] = rsqrtf(v + LN_EPS);
    }
    __syncthreads();
    {
        const float mu = bcast[0], rs = bcast[1];
        float* orow = out + ((size_t)(b*NT + NT - 1))*ND;
        #pragma unroll
        for (int mt = 0; mt < 4; mt++)
          #pragma unroll
          for (int fh = 0; fh < 2; fh++)
            #pragma unroll
            for (int reg = 0; reg < 4; reg++){
                int wp = mt*16 + q*4 + reg;
                if (wp < WP)
                    orow[(size_t)(hp_g*WP + wp)*NF + fh*16 + col] =
                        (hreg[mt][fh][reg] - mu)*rs*gr[mt][fh][reg] + br[mt][fh][reg];
            }
    }
}

extern "C" void kernel_launch(void* const* d_in, const int* in_sizes, int n_in,
                              void* d_out, int out_size, void* d_ws, size_t ws_size,
                              hipStream_t stream)
{
    const float* x     = (const float*)d_in[0];
    const float* Wk    = (const float*)d_in[1];
    const float* Uk    = (const float*)d_in[2];
    const float* bias  = (const float*)d_in[3];
    const float* gamma = (const float*)d_in[4];
    const float* beta  = (const float*)d_in[5];
    float* out = (float*)d_out;

    // ws layout:
    //   hbuf0  bf16  NB*ND          (3.21 MB)
    //   hbuf1  bf16  NB*ND          (3.21 MB)
    //   stats  fp32  NB*NT*2        (3072 B)   \
    //   cnt    int   NB*NT          (1536 B)    } one contiguous memset
    //   flags  int   NT*NB*NHPQ     (21504 B)  /
    char* p = (char*)d_ws;
    ushort* hbuf0 = (ushort*)p; p += (size_t)NB*ND*2;
    ushort* hbuf1 = (ushort*)p; p += (size_t)NB*ND*2;
    float*  stats = (float*)p;  p += (size_t)NB*NT*2*4;
    int*    cnt   = (int*)p;    p += (size_t)NB*NT*4;
    int*    flags = (int*)p;

    hipMemsetAsync(stats, 0, (size_t)(NB*NT*2*4 + NB*NT*4 + NT*NB*NHPQ*4), stream);
    hipLaunchKernelGGL(convlstm_persist, dim3(NHPQ, NB), dim3(256), 0, stream,
                       x, Wk, Uk, bias, gamma, beta,
                       hbuf0, hbuf1, out, stats, cnt, flags);
}